// Round 2
// baseline (7378.739 us; speedup 1.0000x reference)
//
#include <hip/hip_runtime.h>
#include <cstdint>
#include <cstddef>

#define S_LEN 512
#define NB    64
#define NI    1024
#define NH    1024
#define NR    4096   // 4 gates * NH, interleaved r = j*4 + g  (g: 0=i,1=f,2=c,3=o)
#define NWG   128    // persistent workgroups (<= 256 CUs, 1/CU => all resident)

typedef short bf16x8 __attribute__((ext_vector_type(8)));
typedef float f32x4  __attribute__((ext_vector_type(4)));

__device__ __forceinline__ short f2bf(float f) {
  uint32_t u = __float_as_uint(f);
  u += 0x7fff + ((u >> 16) & 1);          // RNE
  return (short)(u >> 16);
}
__device__ __forceinline__ float bf2f(short s) {
  return __uint_as_float(((uint32_t)(uint16_t)s) << 16);
}
__device__ __forceinline__ void gload16(const void* g, void* l) {
  __builtin_amdgcn_global_load_lds((const __attribute__((address_space(1))) void*)g,
                                   (__attribute__((address_space(3))) void*)l, 16, 0, 0);
}
__device__ __forceinline__ float sigm(float x) { return 1.0f / (1.0f + __expf(-x)); }

// ---------------- prep kernels ----------------

__global__ __launch_bounds__(256) void k_convert_x(const float* __restrict__ x,
                                                   short* __restrict__ xbf) {
  int tid = blockIdx.x * 256 + threadIdx.x;        // exactly SB*NI/4 threads
  float4 v = ((const float4*)x)[tid];
  short4 o;
  o.x = f2bf(v.x); o.y = f2bf(v.y); o.z = f2bf(v.z); o.w = f2bf(v.w);
  ((short4*)xbf)[tid] = o;
}

struct WPtrs { const float *xi, *xf, *xc, *xo, *hi, *hf, *hc, *ho; };

__global__ __launch_bounds__(256) void k_pack_w(WPtrs w, short* __restrict__ wxcat,
                                                short* __restrict__ whcat) {
  int tid  = blockIdx.x * 256 + threadIdx.x;       // NR*NI/4 threads
  int flat = tid * 4;
  int r = flat >> 10, k = flat & 1023;
  int j = r >> 2, g = r & 3;
  const float* px = (g == 0) ? w.xi : (g == 1) ? w.xf : (g == 2) ? w.xc : w.xo;
  const float* ph = (g == 0) ? w.hi : (g == 1) ? w.hf : (g == 2) ? w.hc : w.ho;
  float4 vx = *(const float4*)(px + j * 1024 + k);
  float4 vh = *(const float4*)(ph + j * 1024 + k);
  short4 ox, oh;
  ox.x = f2bf(vx.x); ox.y = f2bf(vx.y); ox.z = f2bf(vx.z); ox.w = f2bf(vx.w);
  oh.x = f2bf(vh.x); oh.y = f2bf(vh.y); oh.z = f2bf(vh.z); oh.w = f2bf(vh.w);
  *(short4*)(wxcat + flat) = ox;
  *(short4*)(whcat + flat) = oh;
}

struct BPtrs { const float *xi,*hi,*i_, *xf,*hf,*f_, *xc,*hc,*c_, *xo,*ho,*o_; };

__global__ __launch_bounds__(256) void k_init(BPtrs p, float* __restrict__ bias,
                                              short* __restrict__ h0, short* __restrict__ h1,
                                              unsigned int* __restrict__ bar) {
  int tid = blockIdx.x * 256 + threadIdx.x;        // NB*NH threads
  h0[tid] = 0;
  h1[tid] = 0;
  if (tid < S_LEN) bar[tid] = 0;                   // grid-barrier counters
  if (tid < NR) {
    int j = tid >> 2, g = tid & 3;
    const float* bx = (g == 0) ? p.xi : (g == 1) ? p.xf : (g == 2) ? p.xc : p.xo;
    const float* bh = (g == 0) ? p.hi : (g == 1) ? p.hf : (g == 2) ? p.hc : p.ho;
    const float* bb = (g == 0) ? p.i_ : (g == 1) ? p.f_ : (g == 2) ? p.c_ : p.o_;
    bias[tid] = bx[j] + bh[j] + bb[j];
  }
}

// ---------------- phase 1: gx = x @ Wx^T + bias  (bf16 MFMA, 128x128 tile) --------------

__global__ __launch_bounds__(256) void gemm_x(const short* __restrict__ xbf,  // [32768][1024]
                                              const short* __restrict__ wx,   // [4096][1024]
                                              const float* __restrict__ bias, // [4096]
                                              short* __restrict__ gx) {       // [32768][4096]
  __shared__ __align__(16) short As[2][4096];   // [128][32] bf16, 64B rows
  __shared__ __align__(16) short Bs[2][4096];

  const int tid = threadIdx.x, wave = tid >> 6, lane = tid & 63;
  const int m0 = blockIdx.x * 128, n0 = blockIdx.y * 128;
  const char* aB = (const char*)xbf + (size_t)m0 * 2048;
  const char* bB = (const char*)wx + (size_t)n0 * 2048;

  f32x4 acc[4][4] = {};

  auto stage = [&](int kt, int buf) {
#pragma unroll
    for (int s2 = 0; s2 < 2; ++s2) {
      int seg = wave * 2 + s2;
      int L   = seg * 1024 + lane * 16;
      int row = L >> 6;           // 64-B rows
      int cb  = L & 63;
      gload16(aB + (size_t)row * 2048 + kt * 64 + cb, (char*)&As[buf][0] + L);
      gload16(bB + (size_t)row * 2048 + kt * 64 + cb, (char*)&Bs[buf][0] + L);
    }
  };

  const int wm = wave >> 1, wn = wave & 1;
  auto compute = [&](int buf) {
    const char* Ab = (const char*)&As[buf][0];
    const char* Bb = (const char*)&Bs[buf][0];
    bf16x8 a[4], b[4];
#pragma unroll
    for (int f = 0; f < 4; ++f) {
      int ar = wm * 64 + f * 16 + (lane & 15);
      a[f] = *(const bf16x8*)(Ab + ar * 64 + (lane >> 4) * 16);
      int br = wn * 64 + f * 16 + (lane & 15);
      b[f] = *(const bf16x8*)(Bb + br * 64 + (lane >> 4) * 16);
    }
#pragma unroll
    for (int i = 0; i < 4; ++i)
#pragma unroll
      for (int j = 0; j < 4; ++j)
        acc[i][j] = __builtin_amdgcn_mfma_f32_16x16x32_bf16(a[i], b[j], acc[i][j], 0, 0, 0);
  };

  stage(0, 0);
  __syncthreads();
  int buf = 0;
  for (int kt = 0; kt < 32; ++kt) {
    if (kt < 31) stage(kt + 1, buf ^ 1);
    compute(buf);
    __syncthreads();
    buf ^= 1;
  }

  const int colL = lane & 15;
#pragma unroll
  for (int j = 0; j < 4; ++j) {
    int   n  = n0 + wn * 64 + j * 16 + colL;
    float bv = bias[n];
#pragma unroll
    for (int i = 0; i < 4; ++i) {
#pragma unroll
      for (int q = 0; q < 4; ++q) {
        int m = m0 + wm * 64 + i * 16 + (lane >> 4) * 4 + q;
        gx[(size_t)m * NR + n] = f2bf(acc[i][j][q] + bv);
      }
    }
  }
}

// ---------------- persistent recurrence kernel ----------------
// 128 WGs x 256 threads, 1 WG/CU. WG w owns weight rows [w*32, w*32+32)
// == hidden units j in [w*8, w*8+8), all 4 gates. Wh rows live in LDS for the
// whole kernel (XOR-swizzled). c lives in registers. h double-buffered in
// global; device-scope barrier per step.
//
// Dynamic LDS layout (bytes):
//   [0,      65536)  Wh tile   32 rows x 1024 k bf16 (2048-B rows, XOR-swz)
//   [65536,  98304)  As buf0   64 b x 256 k bf16 (512-B rows, XOR-swz)
//   [98304, 131072)  As buf1
//   [131072,139520)  pre[64][33] f32
//   [139520,147712)  gxs[2]    64 b x 32 r bf16 each
#define LDS_BYTES 147712

__global__ __launch_bounds__(256) void lstm_persist(
    const short* __restrict__ gx,   // [S][64][4096]
    const short* __restrict__ wh,   // [4096][1024]
    short* __restrict__ h0,         // [64][1024]
    short* __restrict__ h1,
    unsigned int* __restrict__ bar, // [S]
    float* __restrict__ out) {
  extern __shared__ __align__(16) char lds[];
  const char* WhC = lds;
  char* As[2] = { lds + 65536, lds + 98304 };
  float (*pre)[33] = (float(*)[33])(lds + 131072);
  char* gxs = lds + 139520;

  const int tid = threadIdx.x, wave = tid >> 6, lane = tid & 63;
  const int r0 = blockIdx.x * 32;
  const int j0 = blockIdx.x * 8;
  const char* whB = (const char*)(wh + (size_t)r0 * NH);

  // ---- load Wh once, swizzled via pre-swizzled global source (rule #21) ----
#pragma unroll
  for (int p = 0; p < 16; ++p) {
    int L = p * 4096 + tid * 16;
    int row = L >> 11, kb = L & 2047;
    gload16(whB + (size_t)row * 2048 + (kb ^ ((row & 7) << 4)), lds + L);
  }

  const int b_pw = tid >> 2;            // pointwise: this thread's batch
  const int jj0  = (tid & 3) * 2;       // and j-pair base (within WG's 8 j)
  float c_reg[2] = {0.f, 0.f};

  auto stageA = [&](const char* hinB, char* dst, int kt) {
#pragma unroll
    for (int s = 0; s < 8; ++s) {
      int L = s * 4096 + tid * 16;
      int row = L >> 9, cb = L & 511;
      gload16(hinB + (size_t)row * 2048 + kt * 512 + (cb ^ ((row & 7) << 4)), dst + L);
    }
  };
  auto stageGX = [&](int tt, char* dst) {
    const char* src = (const char*)gx +
        ((size_t)tt * NB * NR + (size_t)b_pw * NR + r0 + (tid & 3) * 8) * 2;
    gload16(src, dst + tid * 16);
  };

  f32x4 acc[2][2];
  const int arow = wave * 16 + (lane & 15);
  const int aswz = (arow & 7) << 4;
  const int b0r  = lane & 15, b1r = 16 + (lane & 15);
  const int bs0  = (b0r & 7) << 4, bs1 = (b1r & 7) << 4;

  auto compute = [&](const char* Ab, int kt) {
#pragma unroll
    for (int ks = 0; ks < 8; ++ks) {
      int cb = ks * 64 + (lane >> 4) * 16;
      bf16x8 a  = *(const bf16x8*)(Ab + arow * 512 + (cb ^ aswz));
      int wb = kt * 512 + cb;
      bf16x8 b0 = *(const bf16x8*)(WhC + b0r * 2048 + (wb ^ bs0));
      bf16x8 b1 = *(const bf16x8*)(WhC + b1r * 2048 + (wb ^ bs1));
      acc[0][ks & 1] = __builtin_amdgcn_mfma_f32_16x16x32_bf16(a, b0, acc[0][ks & 1], 0, 0, 0);
      acc[1][ks & 1] = __builtin_amdgcn_mfma_f32_16x16x32_bf16(a, b1, acc[1][ks & 1], 0, 0, 0);
    }
  };

  stageGX(0, gxs);   // gx tile for t=0

  for (int t = 0; t < S_LEN; ++t) {
    const short* hin  = (t & 1) ? h1 : h0;
    short*       hout = (t & 1) ? h0 : h1;
    const char*  hinB = (const char*)hin;

    acc[0][0] = (f32x4){}; acc[0][1] = (f32x4){};
    acc[1][0] = (f32x4){}; acc[1][1] = (f32x4){};

    stageA(hinB, As[0], 0);
    if (t + 1 < S_LEN) stageGX(t + 1, gxs + ((t + 1) & 1) * 4096);  // prefetch next gx
    __syncthreads();   // As[0], gx(t) [issued last step], Wh (t=0) all resident

    int buf = 0;
#pragma unroll
    for (int kt = 0; kt < 4; ++kt) {
      if (kt < 3) stageA(hinB, As[buf ^ 1], kt + 1);
      compute(As[buf], kt);
      __syncthreads();
      buf ^= 1;
    }

    // park pre-activations (pre = h @ Wh^T for this WG's 32 rows)
    {
      f32x4 a0 = acc[0][0] + acc[0][1];
      f32x4 a1 = acc[1][0] + acc[1][1];
      const int colL = lane & 15;
      const int mB   = wave * 16 + (lane >> 4) * 4;
#pragma unroll
      for (int q = 0; q < 4; ++q) {
        pre[mB + q][colL]      = a0[q];
        pre[mB + q][colL + 16] = a1[q];
      }
    }
    __syncthreads();

    // pointwise: thread owns (b_pw, jj0..jj0+1)
    bf16x8 gxv = *(const bf16x8*)(gxs + (t & 1) * 4096 + tid * 16);
    float hn2[2];
#pragma unroll
    for (int it = 0; it < 2; ++it) {
      int jj = jj0 + it;
      float vi = pre[b_pw][jj * 4 + 0] + bf2f(gxv[it * 4 + 0]);
      float vf = pre[b_pw][jj * 4 + 1] + bf2f(gxv[it * 4 + 1]);
      float vg = pre[b_pw][jj * 4 + 2] + bf2f(gxv[it * 4 + 2]);
      float vo = pre[b_pw][jj * 4 + 3] + bf2f(gxv[it * 4 + 3]);
      float ig = sigm(vi), fg = sigm(vf), gg = tanhf(vg), og = sigm(vo);
      c_reg[it] = fg * c_reg[it] + ig * gg;
      hn2[it]   = og * tanhf(c_reg[it]);
    }
    // stores: h (bf16, 4B/thread), out (fp32, 8B/thread)
    {
      ushort2 hb = { (ushort)f2bf(hn2[0]), (ushort)f2bf(hn2[1]) };
      *(ushort2*)(hout + b_pw * NH + j0 + jj0) = hb;
      float2 of = { hn2[0], hn2[1] };
      *(float2*)(out + ((size_t)t * NB + b_pw) * NH + j0 + jj0) = of;
      if (t == S_LEN - 1) {
        float* oh = out + (size_t)S_LEN * NB * NH;
        int ci = b_pw * NH + j0 + jj0;
        *(float2*)(oh + ci)           = of;                        // final h
        float2 cf = { c_reg[0], c_reg[1] };
        *(float2*)(oh + NB * NH + ci) = cf;                        // final c
      }
    }

    // device-scope grid barrier (h_t must be visible before anyone reads it)
    if (t != S_LEN - 1) {
      __syncthreads();           // all threads' h stores issued & drained
      if (tid == 0) {
        __threadfence();         // release: flush to coherence point
        atomicAdd(&bar[t], 1u);
        while (__hip_atomic_load(&bar[t], __ATOMIC_RELAXED, __HIP_MEMORY_SCOPE_AGENT)
               < (unsigned)NWG)
          __builtin_amdgcn_s_sleep(2);
        __threadfence();         // acquire: invalidate stale L1/L2
      }
      __syncthreads();
    }
  }
}

// ---------------- launch ----------------

extern "C" void kernel_launch(void* const* d_in, const int* in_sizes, int n_in,
                              void* d_out, int out_size, void* d_ws, size_t ws_size,
                              hipStream_t stream) {
  const float* x   = (const float*)d_in[0];
  const float* wxi = (const float*)d_in[1];
  const float* bxi = (const float*)d_in[2];
  const float* whi = (const float*)d_in[3];
  const float* bhi = (const float*)d_in[4];
  const float* bi  = (const float*)d_in[5];
  const float* wxf = (const float*)d_in[6];
  const float* bxf = (const float*)d_in[7];
  const float* whf = (const float*)d_in[8];
  const float* bhf = (const float*)d_in[9];
  const float* bf  = (const float*)d_in[10];
  const float* wxc = (const float*)d_in[11];
  const float* bxc = (const float*)d_in[12];
  const float* whc = (const float*)d_in[13];
  const float* bhc = (const float*)d_in[14];
  const float* bc  = (const float*)d_in[15];
  const float* wxo = (const float*)d_in[16];
  const float* bxo = (const float*)d_in[17];
  const float* who = (const float*)d_in[18];
  const float* bho = (const float*)d_in[19];
  const float* bo  = (const float*)d_in[20];

  char* ws = (char*)d_ws;
  const size_t SB = (size_t)S_LEN * NB;
  size_t off = 0;
  short* gx    = (short*)(ws + off); off += SB * NR * 2;        // 268 MB
  short* xbf   = (short*)(ws + off); off += SB * NI * 2;        // 67 MB
  short* wxcat = (short*)(ws + off); off += (size_t)NR * NI * 2;
  short* whcat = (short*)(ws + off); off += (size_t)NR * NH * 2;
  float* bias  = (float*)(ws + off); off += NR * 4;
  short* h0    = (short*)(ws + off); off += NB * NH * 2;
  short* h1    = (short*)(ws + off); off += NB * NH * 2;
  unsigned int* bar = (unsigned int*)(ws + off); off += S_LEN * 4;
  (void)ws_size; (void)in_sizes; (void)n_in; (void)out_size;

  float* out = (float*)d_out;

  (void)hipFuncSetAttribute((const void*)lstm_persist,
                            hipFuncAttributeMaxDynamicSharedMemorySize, LDS_BYTES);

  k_convert_x<<<(int)(SB * NI / 4 / 256), 256, 0, stream>>>(x, xbf);
  WPtrs wp = {wxi, wxf, wxc, wxo, whi, whf, whc, who};
  k_pack_w<<<(NR * NI / 4) / 256, 256, 0, stream>>>(wp, wxcat, whcat);
  BPtrs bp = {bxi, bhi, bi, bxf, bhf, bf, bxc, bhc, bc, bxo, bho, bo};
  k_init<<<(NB * NH) / 256, 256, 0, stream>>>(bp, bias, h0, h1, bar);

  gemm_x<<<dim3(SB / 128, NR / 128), 256, 0, stream>>>(xbf, wxcat, bias, gx);

  lstm_persist<<<NWG, 256, LDS_BYTES, stream>>>(gx, whcat, h0, h1, bar, out);
}

// Round 3
// 6213.222 us; speedup vs baseline: 1.1876x; 1.1876x over previous
//
#include <hip/hip_runtime.h>
#include <cstdint>
#include <cstddef>

#define S_LEN 512
#define NB    64
#define NI    1024
#define NH    1024
#define NR    4096   // 4 gates * NH, interleaved r = j*4 + g  (g: 0=i,1=f,2=c,3=o)
#define NWG   128    // persistent workgroups, 1/CU

typedef short bf16x8 __attribute__((ext_vector_type(8)));
typedef float f32x4  __attribute__((ext_vector_type(4)));

__device__ __forceinline__ short f2bf(float f) {
  uint32_t u = __float_as_uint(f);
  u += 0x7fff + ((u >> 16) & 1);          // RNE
  return (short)(u >> 16);
}
__device__ __forceinline__ float bf2f(short s) {
  return __uint_as_float(((uint32_t)(uint16_t)s) << 16);
}
__device__ __forceinline__ void gload16(const void* g, void* l) {
  __builtin_amdgcn_global_load_lds((const __attribute__((address_space(1))) void*)g,
                                   (__attribute__((address_space(3))) void*)l, 16, 0, 0);
}
__device__ __forceinline__ float sigm(float x) { return 1.0f / (1.0f + __expf(-x)); }

// fabric-coherent (cache-bypassing) accesses — no fences needed
__device__ __forceinline__ uint64_t aload64(const void* p) {
  return __hip_atomic_load((const uint64_t*)p, __ATOMIC_RELAXED, __HIP_MEMORY_SCOPE_AGENT);
}
__device__ __forceinline__ void astore32(void* p, uint32_t v) {
  __hip_atomic_store((uint32_t*)p, v, __ATOMIC_RELAXED, __HIP_MEMORY_SCOPE_AGENT);
}

// ---------------- prep kernels ----------------

__global__ __launch_bounds__(256) void k_convert_x(const float* __restrict__ x,
                                                   short* __restrict__ xbf) {
  int tid = blockIdx.x * 256 + threadIdx.x;        // exactly SB*NI/4 threads
  float4 v = ((const float4*)x)[tid];
  short4 o;
  o.x = f2bf(v.x); o.y = f2bf(v.y); o.z = f2bf(v.z); o.w = f2bf(v.w);
  ((short4*)xbf)[tid] = o;
}

struct WPtrs { const float *xi, *xf, *xc, *xo, *hi, *hf, *hc, *ho; };

__global__ __launch_bounds__(256) void k_pack_w(WPtrs w, short* __restrict__ wxcat,
                                                short* __restrict__ whcat) {
  int tid  = blockIdx.x * 256 + threadIdx.x;       // NR*NI/4 threads
  int flat = tid * 4;
  int r = flat >> 10, k = flat & 1023;
  int j = r >> 2, g = r & 3;
  const float* px = (g == 0) ? w.xi : (g == 1) ? w.xf : (g == 2) ? w.xc : w.xo;
  const float* ph = (g == 0) ? w.hi : (g == 1) ? w.hf : (g == 2) ? w.hc : w.ho;
  float4 vx = *(const float4*)(px + j * 1024 + k);
  float4 vh = *(const float4*)(ph + j * 1024 + k);
  short4 ox, oh;
  ox.x = f2bf(vx.x); ox.y = f2bf(vx.y); ox.z = f2bf(vx.z); ox.w = f2bf(vx.w);
  oh.x = f2bf(vh.x); oh.y = f2bf(vh.y); oh.z = f2bf(vh.z); oh.w = f2bf(vh.w);
  *(short4*)(wxcat + flat) = ox;
  *(short4*)(whcat + flat) = oh;
}

struct BPtrs { const float *xi,*hi,*i_, *xf,*hf,*f_, *xc,*hc,*c_, *xo,*ho,*o_; };

__global__ __launch_bounds__(256) void k_init(BPtrs p, float* __restrict__ bias,
                                              short* __restrict__ h0, short* __restrict__ h1,
                                              unsigned int* __restrict__ bar) {
  int tid = blockIdx.x * 256 + threadIdx.x;        // NB*NH threads
  h0[tid] = 0;
  h1[tid] = 0;
  if (tid < S_LEN) bar[tid] = 0;                   // grid-barrier counters
  if (tid < NR) {
    int j = tid >> 2, g = tid & 3;
    const float* bx = (g == 0) ? p.xi : (g == 1) ? p.xf : (g == 2) ? p.xc : p.xo;
    const float* bh = (g == 0) ? p.hi : (g == 1) ? p.hf : (g == 2) ? p.hc : p.ho;
    const float* bb = (g == 0) ? p.i_ : (g == 1) ? p.f_ : (g == 2) ? p.c_ : p.o_;
    bias[tid] = bx[j] + bh[j] + bb[j];
  }
}

// ---------------- phase 1: gx = x @ Wx^T + bias  (bf16 MFMA, 128x128 tile) --------------

__global__ __launch_bounds__(256) void gemm_x(const short* __restrict__ xbf,  // [32768][1024]
                                              const short* __restrict__ wx,   // [4096][1024]
                                              const float* __restrict__ bias, // [4096]
                                              short* __restrict__ gx) {       // [32768][4096]
  __shared__ __align__(16) short As[2][4096];   // [128][32] bf16, 64B rows
  __shared__ __align__(16) short Bs[2][4096];

  const int tid = threadIdx.x, wave = tid >> 6, lane = tid & 63;
  const int m0 = blockIdx.x * 128, n0 = blockIdx.y * 128;
  const char* aB = (const char*)xbf + (size_t)m0 * 2048;
  const char* bB = (const char*)wx + (size_t)n0 * 2048;

  f32x4 acc[4][4] = {};

  auto stage = [&](int kt, int buf) {
#pragma unroll
    for (int s2 = 0; s2 < 2; ++s2) {
      int seg = wave * 2 + s2;
      int L   = seg * 1024 + lane * 16;
      int row = L >> 6;           // 64-B rows
      int cb  = L & 63;
      gload16(aB + (size_t)row * 2048 + kt * 64 + cb, (char*)&As[buf][0] + L);
      gload16(bB + (size_t)row * 2048 + kt * 64 + cb, (char*)&Bs[buf][0] + L);
    }
  };

  const int wm = wave >> 1, wn = wave & 1;
  auto compute = [&](int buf) {
    const char* Ab = (const char*)&As[buf][0];
    const char* Bb = (const char*)&Bs[buf][0];
    bf16x8 a[4], b[4];
#pragma unroll
    for (int f = 0; f < 4; ++f) {
      int ar = wm * 64 + f * 16 + (lane & 15);
      a[f] = *(const bf16x8*)(Ab + ar * 64 + (lane >> 4) * 16);
      int br = wn * 64 + f * 16 + (lane & 15);
      b[f] = *(const bf16x8*)(Bb + br * 64 + (lane >> 4) * 16);
    }
#pragma unroll
    for (int i = 0; i < 4; ++i)
#pragma unroll
      for (int j = 0; j < 4; ++j)
        acc[i][j] = __builtin_amdgcn_mfma_f32_16x16x32_bf16(a[i], b[j], acc[i][j], 0, 0, 0);
  };

  stage(0, 0);
  __syncthreads();
  int buf = 0;
  for (int kt = 0; kt < 32; ++kt) {
    if (kt < 31) stage(kt + 1, buf ^ 1);
    compute(buf);
    __syncthreads();
    buf ^= 1;
  }

  const int colL = lane & 15;
#pragma unroll
  for (int j = 0; j < 4; ++j) {
    int   n  = n0 + wn * 64 + j * 16 + colL;
    float bv = bias[n];
#pragma unroll
    for (int i = 0; i < 4; ++i) {
#pragma unroll
      for (int q = 0; q < 4; ++q) {
        int m = m0 + wm * 64 + i * 16 + (lane >> 4) * 4 + q;
        gx[(size_t)m * NR + n] = f2bf(acc[i][j][q] + bv);
      }
    }
  }
}

// ---------------- persistent recurrence kernel ----------------
// 128 WGs x 256 threads. WG w owns weight rows [w*32, w*32+32) == hidden units
// j in [w*8, w*8+8), all 4 gates. Wh lives in LDS (XOR-swizzled) for the whole
// kernel; c in registers; h ping-pongs through FABRIC (sc0sc1 atomics both
// sides -> no fences, no L2 wbl2/inv). A-fragments load straight to VGPRs.
//
// LDS: [0,65536) Wh 32rows x 1024k bf16 (2048-B rows, XOR-swz); then pre[64][33] f32.
#define LDS_BYTES (65536 + 64 * 33 * 4)

__global__ __launch_bounds__(256) void lstm_persist(
    const short* __restrict__ gx,   // [S][64][4096]
    const short* __restrict__ wh,   // [4096][1024]
    short* __restrict__ h0,         // [64][1024]
    short* __restrict__ h1,
    unsigned int* __restrict__ bar, // [S]
    float* __restrict__ out) {
  extern __shared__ __align__(16) char lds[];
  char* WhC = lds;
  float (*pre)[33] = (float(*)[33])(lds + 65536);

  const int tid = threadIdx.x, wave = tid >> 6, lane = tid & 63;
  const int r0 = blockIdx.x * 32;
  const int j0 = blockIdx.x * 8;
  const char* whB = (const char*)(wh + (size_t)r0 * NH);

  // ---- load Wh once, swizzled via pre-swizzled global source (rule #21) ----
#pragma unroll
  for (int p = 0; p < 16; ++p) {
    int L = p * 4096 + tid * 16;
    int row = L >> 11, kb = L & 2047;
    gload16(whB + (size_t)row * 2048 + (kb ^ ((row & 7) << 4)), lds + L);
  }

  const int b_pw = tid >> 2;            // pointwise: this thread's batch
  const int jj0  = (tid & 3) * 2;       // j-pair base within WG's 8 j
  float c_reg[2] = {0.f, 0.f};

  // A-fragment addressing: batch row + k-chunk per lane
  const int am   = wave * 16 + (lane & 15);       // batch row (this wave's group)
  const int akb  = (lane >> 4) * 16;              // byte offset of lane's k-chunk
  // B (Wh) fragment addressing
  const int b0r = lane & 15, b1r = 16 + (lane & 15);
  const int bs0 = (b0r & 7) << 4, bs1 = (b1r & 7) << 4;
  const int bcol = (lane >> 4) * 16;

  __syncthreads();   // Wh resident (compiler drains vmcnt before s_barrier)

  for (int t = 0; t < S_LEN; ++t) {
    const short* hin  = (t & 1) ? h1 : h0;
    short*       hout = (t & 1) ? h0 : h1;
    const char*  hinB = (const char*)hin;

    // gx fragment for this thread's pointwise (plain cached load, read-only)
    bf16x8 gxv = *(const bf16x8*)(gx + ((size_t)t * NB + b_pw) * NR + r0 + (tid & 3) * 8);

    // ---- load ALL A-fragments for this step straight to registers (fabric) ----
    bf16x8 a[32];
#pragma unroll
    for (int ks = 0; ks < 32; ++ks) {
      const char* p = hinB + (size_t)am * 2048 + ks * 64 + akb;
      union { uint64_t u[2]; bf16x8 v; } cv;
      cv.u[0] = aload64(p);
      cv.u[1] = aload64(p + 8);
      a[ks] = cv.v;
    }

    // ---- 32 K-steps of MFMA against LDS-resident Wh ----
    f32x4 acc[2][2] = {};
#pragma unroll
    for (int ks = 0; ks < 32; ++ks) {
      int wb = ks * 64 + bcol;
      bf16x8 b0 = *(const bf16x8*)(WhC + b0r * 2048 + (wb ^ bs0));
      bf16x8 b1 = *(const bf16x8*)(WhC + b1r * 2048 + (wb ^ bs1));
      acc[0][ks & 1] = __builtin_amdgcn_mfma_f32_16x16x32_bf16(a[ks], b0, acc[0][ks & 1], 0, 0, 0);
      acc[1][ks & 1] = __builtin_amdgcn_mfma_f32_16x16x32_bf16(a[ks], b1, acc[1][ks & 1], 0, 0, 0);
    }

    // park pre-activations in LDS (remap MFMA layout -> per-(b,j) threads)
    {
      f32x4 a0 = acc[0][0] + acc[0][1];
      f32x4 a1 = acc[1][0] + acc[1][1];
      const int colL = lane & 15;
      const int mB   = wave * 16 + (lane >> 4) * 4;
#pragma unroll
      for (int q = 0; q < 4; ++q) {
        pre[mB + q][colL]      = a0[q];
        pre[mB + q][colL + 16] = a1[q];
      }
    }
    __syncthreads();

    // pointwise: thread owns (b_pw, jj0..jj0+1)
    float hn2[2];
#pragma unroll
    for (int it = 0; it < 2; ++it) {
      int jj = jj0 + it;
      float vi = pre[b_pw][jj * 4 + 0] + bf2f(gxv[it * 4 + 0]);
      float vf = pre[b_pw][jj * 4 + 1] + bf2f(gxv[it * 4 + 1]);
      float vg = pre[b_pw][jj * 4 + 2] + bf2f(gxv[it * 4 + 2]);
      float vo = pre[b_pw][jj * 4 + 3] + bf2f(gxv[it * 4 + 3]);
      float ig = sigm(vi), fg = sigm(vf), gg = tanhf(vg), og = sigm(vo);
      c_reg[it] = fg * c_reg[it] + ig * gg;
      hn2[it]   = og * tanhf(c_reg[it]);
    }
    __syncthreads();   // pre[] free for next step after this

    // h store: write-through to fabric (2 bf16 packed in 1 dword)
    {
      uint32_t hb = (uint32_t)(uint16_t)f2bf(hn2[0]) |
                    ((uint32_t)(uint16_t)f2bf(hn2[1]) << 16);
      astore32(hout + b_pw * NH + j0 + jj0, hb);
      float2 of = { hn2[0], hn2[1] };
      *(float2*)(out + ((size_t)t * NB + b_pw) * NH + j0 + jj0) = of;
      if (t == S_LEN - 1) {
        float* oh = out + (size_t)S_LEN * NB * NH;
        int ci = b_pw * NH + j0 + jj0;
        *(float2*)(oh + ci) = of;                                  // final h
        float2 cf = { c_reg[0], c_reg[1] };
        *(float2*)(oh + NB * NH + ci) = cf;                        // final c
      }
    }

    // grid barrier: vmcnt drained by syncthreads; relaxed fabric atomics only
    if (t != S_LEN - 1) {
      __syncthreads();   // all waves' h stores acked at coherence point
      if (tid == 0) {
        __hip_atomic_fetch_add(&bar[t], 1u, __ATOMIC_RELAXED, __HIP_MEMORY_SCOPE_AGENT);
        while (__hip_atomic_load(&bar[t], __ATOMIC_RELAXED, __HIP_MEMORY_SCOPE_AGENT)
               < (unsigned)NWG)
          __builtin_amdgcn_s_sleep(2);
      }
      __syncthreads();
    }
  }
}

// ---------------- launch ----------------

extern "C" void kernel_launch(void* const* d_in, const int* in_sizes, int n_in,
                              void* d_out, int out_size, void* d_ws, size_t ws_size,
                              hipStream_t stream) {
  const float* x   = (const float*)d_in[0];
  const float* wxi = (const float*)d_in[1];
  const float* bxi = (const float*)d_in[2];
  const float* whi = (const float*)d_in[3];
  const float* bhi = (const float*)d_in[4];
  const float* bi  = (const float*)d_in[5];
  const float* wxf = (const float*)d_in[6];
  const float* bxf = (const float*)d_in[7];
  const float* whf = (const float*)d_in[8];
  const float* bhf = (const float*)d_in[9];
  const float* bf  = (const float*)d_in[10];
  const float* wxc = (const float*)d_in[11];
  const float* bxc = (const float*)d_in[12];
  const float* whc = (const float*)d_in[13];
  const float* bhc = (const float*)d_in[14];
  const float* bc  = (const float*)d_in[15];
  const float* wxo = (const float*)d_in[16];
  const float* bxo = (const float*)d_in[17];
  const float* who = (const float*)d_in[18];
  const float* bho = (const float*)d_in[19];
  const float* bo  = (const float*)d_in[20];

  char* ws = (char*)d_ws;
  const size_t SB = (size_t)S_LEN * NB;
  size_t off = 0;
  short* gxp   = (short*)(ws + off); off += SB * NR * 2;        // 268 MB
  short* xbf   = (short*)(ws + off); off += SB * NI * 2;        // 67 MB
  short* wxcat = (short*)(ws + off); off += (size_t)NR * NI * 2;
  short* whcat = (short*)(ws + off); off += (size_t)NR * NH * 2;
  float* bias  = (float*)(ws + off); off += NR * 4;
  short* h0    = (short*)(ws + off); off += NB * NH * 2;
  short* h1    = (short*)(ws + off); off += NB * NH * 2;
  unsigned int* bar = (unsigned int*)(ws + off); off += S_LEN * 4;
  (void)ws_size; (void)in_sizes; (void)n_in; (void)out_size;

  float* out = (float*)d_out;

  (void)hipFuncSetAttribute((const void*)lstm_persist,
                            hipFuncAttributeMaxDynamicSharedMemorySize, LDS_BYTES);

  k_convert_x<<<(int)(SB * NI / 4 / 256), 256, 0, stream>>>(x, xbf);
  WPtrs wp = {wxi, wxf, wxc, wxo, whi, whf, whc, who};
  k_pack_w<<<(NR * NI / 4) / 256, 256, 0, stream>>>(wp, wxcat, whcat);
  BPtrs bp = {bxi, bhi, bi, bxf, bhf, bf, bxc, bhc, bc, bxo, bho, bo};
  k_init<<<(NB * NH) / 256, 256, 0, stream>>>(bp, bias, h0, h1, bar);

  gemm_x<<<dim3(SB / 128, NR / 128), 256, 0, stream>>>(xbf, wxcat, bias, gxp);

  lstm_persist<<<NWG, 256, LDS_BYTES, stream>>>(gxp, whcat, h0, h1, bar, out);
}

// Round 4
// 4108.390 us; speedup vs baseline: 1.7960x; 1.5123x over previous
//
#include <hip/hip_runtime.h>
#include <cstdint>
#include <cstddef>

#define S_LEN 512
#define NB    64
#define NI    1024
#define NH    1024
#define NR    4096   // 4 gates * NH, interleaved r = j*4 + g  (g: 0=i,1=f,2=c,3=o)
#define NWG   128    // persistent workgroups, 1/CU
#define HSTRIDE 132096  // 128KB h slot + 1KB pad (fresh address per step)

typedef short bf16x8 __attribute__((ext_vector_type(8)));
typedef float f32x4  __attribute__((ext_vector_type(4)));

__device__ __forceinline__ short f2bf(float f) {
  uint32_t u = __float_as_uint(f);
  u += 0x7fff + ((u >> 16) & 1);          // RNE
  return (short)(u >> 16);
}
__device__ __forceinline__ float bf2f(short s) {
  return __uint_as_float(((uint32_t)(uint16_t)s) << 16);
}
__device__ __forceinline__ void gload16(const void* g, void* l) {
  __builtin_amdgcn_global_load_lds((const __attribute__((address_space(1))) void*)g,
                                   (__attribute__((address_space(3))) void*)l, 16, 0, 0);
}
__device__ __forceinline__ float sigm(float x) { return 1.0f / (1.0f + __expf(-x)); }

// write-through store to the coherence point (no fences needed)
__device__ __forceinline__ void astore32(void* p, uint32_t v) {
  __hip_atomic_store((uint32_t*)p, v, __ATOMIC_RELAXED, __HIP_MEMORY_SCOPE_AGENT);
}

// ---------------- prep kernels ----------------

__global__ __launch_bounds__(256) void k_convert_x(const float* __restrict__ x,
                                                   short* __restrict__ xbf) {
  int tid = blockIdx.x * 256 + threadIdx.x;        // exactly SB*NI/4 threads
  float4 v = ((const float4*)x)[tid];
  short4 o;
  o.x = f2bf(v.x); o.y = f2bf(v.y); o.z = f2bf(v.z); o.w = f2bf(v.w);
  ((short4*)xbf)[tid] = o;
}

struct WPtrs { const float *xi, *xf, *xc, *xo, *hi, *hf, *hc, *ho; };

__global__ __launch_bounds__(256) void k_pack_w(WPtrs w, short* __restrict__ wxcat,
                                                short* __restrict__ whcat) {
  int tid  = blockIdx.x * 256 + threadIdx.x;       // NR*NI/4 threads
  int flat = tid * 4;
  int r = flat >> 10, k = flat & 1023;
  int j = r >> 2, g = r & 3;
  const float* px = (g == 0) ? w.xi : (g == 1) ? w.xf : (g == 2) ? w.xc : w.xo;
  const float* ph = (g == 0) ? w.hi : (g == 1) ? w.hf : (g == 2) ? w.hc : w.ho;
  float4 vx = *(const float4*)(px + j * 1024 + k);
  float4 vh = *(const float4*)(ph + j * 1024 + k);
  short4 ox, oh;
  ox.x = f2bf(vx.x); ox.y = f2bf(vx.y); ox.z = f2bf(vx.z); ox.w = f2bf(vx.w);
  oh.x = f2bf(vh.x); oh.y = f2bf(vh.y); oh.z = f2bf(vh.z); oh.w = f2bf(vh.w);
  *(short4*)(wxcat + flat) = ox;
  *(short4*)(whcat + flat) = oh;
}

struct BPtrs { const float *xi,*hi,*i_, *xf,*hf,*f_, *xc,*hc,*c_, *xo,*ho,*o_; };

__global__ __launch_bounds__(256) void k_init(BPtrs p, float* __restrict__ bias,
                                              unsigned int* __restrict__ bar) {
  int tid = blockIdx.x * 256 + threadIdx.x;        // NR threads
  if (tid < S_LEN) bar[tid] = 0;                   // grid-barrier counters
  int j = tid >> 2, g = tid & 3;
  const float* bx = (g == 0) ? p.xi : (g == 1) ? p.xf : (g == 2) ? p.xc : p.xo;
  const float* bh = (g == 0) ? p.hi : (g == 1) ? p.hf : (g == 2) ? p.hc : p.ho;
  const float* bb = (g == 0) ? p.i_ : (g == 1) ? p.f_ : (g == 2) ? p.c_ : p.o_;
  bias[tid] = bx[j] + bh[j] + bb[j];
}

// ---------------- phase 1: gx = x @ Wx^T + bias  (bf16 MFMA, 128x128 tile) --------------

__global__ __launch_bounds__(256) void gemm_x(const short* __restrict__ xbf,  // [32768][1024]
                                              const short* __restrict__ wx,   // [4096][1024]
                                              const float* __restrict__ bias, // [4096]
                                              short* __restrict__ gx) {       // [32768][4096]
  __shared__ __align__(16) short As[2][4096];   // [128][32] bf16, 64B rows
  __shared__ __align__(16) short Bs[2][4096];

  const int tid = threadIdx.x, wave = tid >> 6, lane = tid & 63;
  const int m0 = blockIdx.x * 128, n0 = blockIdx.y * 128;
  const char* aB = (const char*)xbf + (size_t)m0 * 2048;
  const char* bB = (const char*)wx + (size_t)n0 * 2048;

  f32x4 acc[4][4] = {};

  auto stage = [&](int kt, int buf) {
#pragma unroll
    for (int s2 = 0; s2 < 2; ++s2) {
      int seg = wave * 2 + s2;
      int L   = seg * 1024 + lane * 16;
      int row = L >> 6;           // 64-B rows
      int cb  = L & 63;
      gload16(aB + (size_t)row * 2048 + kt * 64 + cb, (char*)&As[buf][0] + L);
      gload16(bB + (size_t)row * 2048 + kt * 64 + cb, (char*)&Bs[buf][0] + L);
    }
  };

  const int wm = wave >> 1, wn = wave & 1;
  auto compute = [&](int buf) {
    const char* Ab = (const char*)&As[buf][0];
    const char* Bb = (const char*)&Bs[buf][0];
    bf16x8 a[4], b[4];
#pragma unroll
    for (int f = 0; f < 4; ++f) {
      int ar = wm * 64 + f * 16 + (lane & 15);
      a[f] = *(const bf16x8*)(Ab + ar * 64 + (lane >> 4) * 16);
      int br = wn * 64 + f * 16 + (lane & 15);
      b[f] = *(const bf16x8*)(Bb + br * 64 + (lane >> 4) * 16);
    }
#pragma unroll
    for (int i = 0; i < 4; ++i)
#pragma unroll
      for (int j = 0; j < 4; ++j)
        acc[i][j] = __builtin_amdgcn_mfma_f32_16x16x32_bf16(a[i], b[j], acc[i][j], 0, 0, 0);
  };

  stage(0, 0);
  __syncthreads();
  int buf = 0;
  for (int kt = 0; kt < 32; ++kt) {
    if (kt < 31) stage(kt + 1, buf ^ 1);
    compute(buf);
    __syncthreads();
    buf ^= 1;
  }

  const int colL = lane & 15;
#pragma unroll
  for (int j = 0; j < 4; ++j) {
    int   n  = n0 + wn * 64 + j * 16 + colL;
    float bv = bias[n];
#pragma unroll
    for (int i = 0; i < 4; ++i) {
#pragma unroll
      for (int q = 0; q < 4; ++q) {
        int m = m0 + wm * 64 + i * 16 + (lane >> 4) * 4 + q;
        gx[(size_t)m * NR + n] = f2bf(acc[i][j][q] + bv);
      }
    }
  }
}

// ---------------- persistent recurrence kernel ----------------
// 128 WGs x 256 threads. WG w owns weight rows [w*32, w*32+32) == hidden units
// j in [w*8, w*8+8), all 4 gates. Wh lives in LDS (XOR-swizzled) for the whole
// kernel; c in registers. h goes through a ROTATING buffer: step t writes slot
// t (write-through fabric stores), step t+1 reads slot t with PLAIN CACHED
// loads — a fresh address can never be stale in L1/L2, so no fences and full
// L2 reuse (16 WGs/XCD share one fabric fill).
//
// LDS: [0,65536) Wh 32rows x 1024k bf16 (2048-B rows, XOR-swz); pre[2][64][33] f32.
#define LDS_BYTES (65536 + 2 * 64 * 33 * 4)

__global__ __launch_bounds__(256) void lstm_persist(
    const short* __restrict__ gx,   // [S][64][4096]
    const short* __restrict__ wh,   // [4096][1024]
    char* __restrict__ hb,          // rotating h slots, HSTRIDE apart
    unsigned int* __restrict__ bar, // [S]
    float* __restrict__ out) {
  extern __shared__ __align__(16) char lds[];
  char* WhC = lds;
  float (*pre)[64][33] = (float(*)[64][33])(lds + 65536);

  const int tid = threadIdx.x, wave = tid >> 6, lane = tid & 63;
  const int r0 = blockIdx.x * 32;
  const int j0 = blockIdx.x * 8;
  const char* whB = (const char*)(wh + (size_t)r0 * NH);

  // ---- load Wh once, swizzled via pre-swizzled global source (rule #21) ----
#pragma unroll
  for (int p = 0; p < 16; ++p) {
    int L = p * 4096 + tid * 16;
    int row = L >> 11, kb = L & 2047;
    gload16(whB + (size_t)row * 2048 + (kb ^ ((row & 7) << 4)), lds + L);
  }

  const int b_pw = tid >> 2;            // pointwise: this thread's batch
  const int jj0  = (tid & 3) * 2;       // j-pair base within WG's 8 j
  float c_reg[2] = {0.f, 0.f};

  // A-fragment addressing: batch row + k-chunk per lane
  const int am   = wave * 16 + (lane & 15);       // batch row
  const int akb  = (lane >> 4) * 16;              // lane's 16-B k-chunk
  // B (Wh) fragment addressing
  const int b0r = lane & 15, b1r = 16 + (lane & 15);
  const int bs0 = (b0r & 7) << 4, bs1 = (b1r & 7) << 4;
  const int bcol = (lane >> 4) * 16;

  __syncthreads();   // Wh resident

  // gx fragment for t=0
  bf16x8 gxv = *(const bf16x8*)(gx + (size_t)b_pw * NR + r0 + (tid & 3) * 8);

  for (int t = 0; t < S_LEN; ++t) {
    f32x4 acc[2][2] = {};

    if (t) {   // t=0: h=0 -> matvec contributes nothing
      const char* hs = hb + (size_t)(t - 1) * HSTRIDE + (size_t)am * 2048 + akb;
      // cached 16-B loads straight into A-fragments (L2-shared across WGs/XCD)
      bf16x8 a[32];
#pragma unroll
      for (int ks = 0; ks < 32; ++ks)
        a[ks] = *(const bf16x8*)(hs + ks * 64);
#pragma unroll
      for (int ks = 0; ks < 32; ++ks) {
        int wb = ks * 64 + bcol;
        bf16x8 b0 = *(const bf16x8*)(WhC + b0r * 2048 + (wb ^ bs0));
        bf16x8 b1 = *(const bf16x8*)(WhC + b1r * 2048 + (wb ^ bs1));
        acc[0][ks & 1] = __builtin_amdgcn_mfma_f32_16x16x32_bf16(a[ks], b0, acc[0][ks & 1], 0, 0, 0);
        acc[1][ks & 1] = __builtin_amdgcn_mfma_f32_16x16x32_bf16(a[ks], b1, acc[1][ks & 1], 0, 0, 0);
      }
    }

    // park pre-activations in LDS (parity buffer; remap MFMA layout)
    const int par = t & 1;
    {
      f32x4 a0 = acc[0][0] + acc[0][1];
      f32x4 a1 = acc[1][0] + acc[1][1];
      const int colL = lane & 15;
      const int mB   = wave * 16 + (lane >> 4) * 4;
#pragma unroll
      for (int q = 0; q < 4; ++q) {
        pre[par][mB + q][colL]      = a0[q];
        pre[par][mB + q][colL + 16] = a1[q];
      }
    }
    __syncthreads();

    // pointwise: thread owns (b_pw, jj0..jj0+1)
    float hn2[2];
#pragma unroll
    for (int it = 0; it < 2; ++it) {
      int jj = jj0 + it;
      float vi = pre[par][b_pw][jj * 4 + 0] + bf2f(gxv[it * 4 + 0]);
      float vf = pre[par][b_pw][jj * 4 + 1] + bf2f(gxv[it * 4 + 1]);
      float vg = pre[par][b_pw][jj * 4 + 2] + bf2f(gxv[it * 4 + 2]);
      float vo = pre[par][b_pw][jj * 4 + 3] + bf2f(gxv[it * 4 + 3]);
      float ig = sigm(vi), fg = sigm(vf), gg = tanhf(vg), og = sigm(vo);
      c_reg[it] = fg * c_reg[it] + ig * gg;
      hn2[it]   = og * tanhf(c_reg[it]);
    }

    // h store: write-through to fabric (2 bf16 in 1 dword) into slot t
    {
      short* hout = (short*)(hb + (size_t)t * HSTRIDE);
      uint32_t hbits = (uint32_t)(uint16_t)f2bf(hn2[0]) |
                       ((uint32_t)(uint16_t)f2bf(hn2[1]) << 16);
      astore32(hout + b_pw * NH + j0 + jj0, hbits);
      float2 of = { hn2[0], hn2[1] };
      *(float2*)(out + ((size_t)t * NB + b_pw) * NH + j0 + jj0) = of;
      if (t == S_LEN - 1) {
        float* oh = out + (size_t)S_LEN * NB * NH;
        int ci = b_pw * NH + j0 + jj0;
        *(float2*)(oh + ci) = of;                                  // final h
        float2 cf = { c_reg[0], c_reg[1] };
        *(float2*)(oh + NB * NH + ci) = cf;                        // final c
      }
    }

    if (t != S_LEN - 1) {
      // prefetch next gx fragment (independent of barrier)
      gxv = *(const bf16x8*)(gx + ((size_t)(t + 1) * NB + b_pw) * NR + r0 + (tid & 3) * 8);
      __syncthreads();   // all waves' h stores acked at coherence point
      if (tid == 0) {
        __hip_atomic_fetch_add(&bar[t], 1u, __ATOMIC_RELAXED, __HIP_MEMORY_SCOPE_AGENT);
        while (__hip_atomic_load(&bar[t], __ATOMIC_RELAXED, __HIP_MEMORY_SCOPE_AGENT)
               < (unsigned)NWG)
          __builtin_amdgcn_s_sleep(2);
      }
      __syncthreads();   // release: h slot t globally visible & fresh
    }
  }
}

// ---------------- launch ----------------

extern "C" void kernel_launch(void* const* d_in, const int* in_sizes, int n_in,
                              void* d_out, int out_size, void* d_ws, size_t ws_size,
                              hipStream_t stream) {
  const float* x   = (const float*)d_in[0];
  const float* wxi = (const float*)d_in[1];
  const float* bxi = (const float*)d_in[2];
  const float* whi = (const float*)d_in[3];
  const float* bhi = (const float*)d_in[4];
  const float* bi  = (const float*)d_in[5];
  const float* wxf = (const float*)d_in[6];
  const float* bxf = (const float*)d_in[7];
  const float* whf = (const float*)d_in[8];
  const float* bhf = (const float*)d_in[9];
  const float* bf  = (const float*)d_in[10];
  const float* wxc = (const float*)d_in[11];
  const float* bxc = (const float*)d_in[12];
  const float* whc = (const float*)d_in[13];
  const float* bhc = (const float*)d_in[14];
  const float* bc  = (const float*)d_in[15];
  const float* wxo = (const float*)d_in[16];
  const float* bxo = (const float*)d_in[17];
  const float* who = (const float*)d_in[18];
  const float* bho = (const float*)d_in[19];
  const float* bo  = (const float*)d_in[20];

  char* ws = (char*)d_ws;
  const size_t SB = (size_t)S_LEN * NB;
  size_t off = 0;
  short* gxp   = (short*)(ws + off); off += SB * NR * 2;        // 268 MB
  short* xbf   = (short*)(ws + off); off += SB * NI * 2;        // 67 MB (dead after gemm_x)
  short* wxcat = (short*)(ws + off); off += (size_t)NR * NI * 2; // 8 MB (dead after gemm_x)
  short* whcat = (short*)(ws + off); off += (size_t)NR * NH * 2;
  float* bias  = (float*)(ws + off); off += NR * 4;
  unsigned int* bar = (unsigned int*)(ws + off); off += S_LEN * 4;
  (void)ws_size; (void)in_sizes; (void)n_in; (void)out_size;

  // rotating h buffer ALIASES xbf+wxcat (both dead once lstm_persist runs):
  // 512 slots x 132096 B = 67.6 MB <= 75.5 MB available.
  char* hb = (char*)xbf;

  float* out = (float*)d_out;

  (void)hipFuncSetAttribute((const void*)lstm_persist,
                            hipFuncAttributeMaxDynamicSharedMemorySize, LDS_BYTES);

  k_convert_x<<<(int)(SB * NI / 4 / 256), 256, 0, stream>>>(x, xbf);
  WPtrs wp = {wxi, wxf, wxc, wxo, whi, whf, whc, who};
  k_pack_w<<<(NR * NI / 4) / 256, 256, 0, stream>>>(wp, wxcat, whcat);
  BPtrs bp = {bxi, bhi, bi, bxf, bhf, bf, bxc, bhc, bc, bxo, bho, bo};
  k_init<<<NR / 256, 256, 0, stream>>>(bp, bias, bar);

  gemm_x<<<dim3(SB / 128, NR / 128), 256, 0, stream>>>(xbf, wxcat, bias, gxp);

  lstm_persist<<<NWG, 256, LDS_BYTES, stream>>>(gxp, whcat, hb, bar, out);
}

// Round 5
// 3635.110 us; speedup vs baseline: 2.0299x; 1.1302x over previous
//
#include <hip/hip_runtime.h>
#include <cstdint>
#include <cstddef>

#define S_LEN 512
#define NB    64
#define NI    1024
#define NH    1024
#define NR    4096   // 4 gates * NH, interleaved r = j*4 + g  (g: 0=i,1=f,2=c,3=o)
#define NWG   128    // persistent workgroups, 1/CU
#define HSTRIDE 132096  // 128KB h slot + 1KB pad (fresh address per step)
#define FLAGSTRIDE 16   // dwords between barrier flags (64 B)

typedef short bf16x8 __attribute__((ext_vector_type(8)));
typedef float f32x4  __attribute__((ext_vector_type(4)));

__device__ __forceinline__ short f2bf(float f) {
  uint32_t u = __float_as_uint(f);
  u += 0x7fff + ((u >> 16) & 1);          // RNE
  return (short)(u >> 16);
}
__device__ __forceinline__ float bf2f(short s) {
  return __uint_as_float(((uint32_t)(uint16_t)s) << 16);
}
__device__ __forceinline__ void gload16(const void* g, void* l) {
  __builtin_amdgcn_global_load_lds((const __attribute__((address_space(1))) void*)g,
                                   (__attribute__((address_space(3))) void*)l, 16, 0, 0);
}
__device__ __forceinline__ float sigm(float x) { return 1.0f / (1.0f + __expf(-x)); }
__device__ __forceinline__ float tanh_fast(float x) {
  return 2.0f / (1.0f + __expf(-2.0f * x)) - 1.0f;   // saturates correctly for |x| large
}

// fabric write-through / uncached read (no fences needed)
__device__ __forceinline__ void astore32(void* p, uint32_t v) {
  __hip_atomic_store((uint32_t*)p, v, __ATOMIC_RELAXED, __HIP_MEMORY_SCOPE_AGENT);
}
__device__ __forceinline__ uint32_t aload32(const void* p) {
  return __hip_atomic_load((const uint32_t*)p, __ATOMIC_RELAXED, __HIP_MEMORY_SCOPE_AGENT);
}

// ---------------- prep kernels ----------------

__global__ __launch_bounds__(256) void k_convert_x(const float* __restrict__ x,
                                                   short* __restrict__ xbf) {
  int tid = blockIdx.x * 256 + threadIdx.x;        // exactly SB*NI/4 threads
  float4 v = ((const float4*)x)[tid];
  short4 o;
  o.x = f2bf(v.x); o.y = f2bf(v.y); o.z = f2bf(v.z); o.w = f2bf(v.w);
  ((short4*)xbf)[tid] = o;
}

struct WPtrs { const float *xi, *xf, *xc, *xo, *hi, *hf, *hc, *ho; };

__global__ __launch_bounds__(256) void k_pack_w(WPtrs w, short* __restrict__ wxcat,
                                                short* __restrict__ whcat) {
  int tid  = blockIdx.x * 256 + threadIdx.x;       // NR*NI/4 threads
  int flat = tid * 4;
  int r = flat >> 10, k = flat & 1023;
  int j = r >> 2, g = r & 3;
  const float* px = (g == 0) ? w.xi : (g == 1) ? w.xf : (g == 2) ? w.xc : w.xo;
  const float* ph = (g == 0) ? w.hi : (g == 1) ? w.hf : (g == 2) ? w.hc : w.ho;
  float4 vx = *(const float4*)(px + j * 1024 + k);
  float4 vh = *(const float4*)(ph + j * 1024 + k);
  short4 ox, oh;
  ox.x = f2bf(vx.x); ox.y = f2bf(vx.y); ox.z = f2bf(vx.z); ox.w = f2bf(vx.w);
  oh.x = f2bf(vh.x); oh.y = f2bf(vh.y); oh.z = f2bf(vh.z); oh.w = f2bf(vh.w);
  *(short4*)(wxcat + flat) = ox;
  *(short4*)(whcat + flat) = oh;
}

struct BPtrs { const float *xi,*hi,*i_, *xf,*hf,*f_, *xc,*hc,*c_, *xo,*ho,*o_; };

__global__ __launch_bounds__(256) void k_init(BPtrs p, float* __restrict__ bias,
                                              unsigned int* __restrict__ flags) {
  int tid = blockIdx.x * 256 + threadIdx.x;        // NR threads
  if (tid < NWG * FLAGSTRIDE) flags[tid] = 0;      // barrier flag array
  int j = tid >> 2, g = tid & 3;
  const float* bx = (g == 0) ? p.xi : (g == 1) ? p.xf : (g == 2) ? p.xc : p.xo;
  const float* bh = (g == 0) ? p.hi : (g == 1) ? p.hf : (g == 2) ? p.hc : p.ho;
  const float* bb = (g == 0) ? p.i_ : (g == 1) ? p.f_ : (g == 2) ? p.c_ : p.o_;
  bias[tid] = bx[j] + bh[j] + bb[j];
}

// ---------------- phase 1: gx = x @ Wx^T + bias  (bf16 MFMA, 128x128 tile) --------------

__global__ __launch_bounds__(256) void gemm_x(const short* __restrict__ xbf,  // [32768][1024]
                                              const short* __restrict__ wx,   // [4096][1024]
                                              const float* __restrict__ bias, // [4096]
                                              short* __restrict__ gx) {       // [32768][4096]
  __shared__ __align__(16) short As[2][4096];   // [128][32] bf16, 64B rows
  __shared__ __align__(16) short Bs[2][4096];

  const int tid = threadIdx.x, wave = tid >> 6, lane = tid & 63;
  const int m0 = blockIdx.x * 128, n0 = blockIdx.y * 128;
  const char* aB = (const char*)xbf + (size_t)m0 * 2048;
  const char* bB = (const char*)wx + (size_t)n0 * 2048;

  f32x4 acc[4][4] = {};

  auto stage = [&](int kt, int buf) {
#pragma unroll
    for (int s2 = 0; s2 < 2; ++s2) {
      int seg = wave * 2 + s2;
      int L   = seg * 1024 + lane * 16;
      int row = L >> 6;           // 64-B rows
      int cb  = L & 63;
      gload16(aB + (size_t)row * 2048 + kt * 64 + cb, (char*)&As[buf][0] + L);
      gload16(bB + (size_t)row * 2048 + kt * 64 + cb, (char*)&Bs[buf][0] + L);
    }
  };

  const int wm = wave >> 1, wn = wave & 1;
  auto compute = [&](int buf) {
    const char* Ab = (const char*)&As[buf][0];
    const char* Bb = (const char*)&Bs[buf][0];
    bf16x8 a[4], b[4];
#pragma unroll
    for (int f = 0; f < 4; ++f) {
      int ar = wm * 64 + f * 16 + (lane & 15);
      a[f] = *(const bf16x8*)(Ab + ar * 64 + (lane >> 4) * 16);
      int br = wn * 64 + f * 16 + (lane & 15);
      b[f] = *(const bf16x8*)(Bb + br * 64 + (lane >> 4) * 16);
    }
#pragma unroll
    for (int i = 0; i < 4; ++i)
#pragma unroll
      for (int j = 0; j < 4; ++j)
        acc[i][j] = __builtin_amdgcn_mfma_f32_16x16x32_bf16(a[i], b[j], acc[i][j], 0, 0, 0);
  };

  stage(0, 0);
  __syncthreads();
  int buf = 0;
  for (int kt = 0; kt < 32; ++kt) {
    if (kt < 31) stage(kt + 1, buf ^ 1);
    compute(buf);
    __syncthreads();
    buf ^= 1;
  }

  const int colL = lane & 15;
#pragma unroll
  for (int j = 0; j < 4; ++j) {
    int   n  = n0 + wn * 64 + j * 16 + colL;
    float bv = bias[n];
#pragma unroll
    for (int i = 0; i < 4; ++i) {
#pragma unroll
      for (int q = 0; q < 4; ++q) {
        int m = m0 + wm * 64 + i * 16 + (lane >> 4) * 4 + q;
        gx[(size_t)m * NR + n] = f2bf(acc[i][j][q] + bv);
      }
    }
  }
}

// ---------------- persistent recurrence kernel ----------------
// 128 WGs x 256 threads. WG w owns weight rows [w*32, w*32+32) == hidden units
// j in [w*8, w*8+8), all 4 gates. Wh lives in LDS (XOR-swizzled); c in regs.
// h rotates through fresh 128-KB slots (write-through stores, plain cached
// reads). Grid barrier = FLAG ARRAY: 1 parallel store per WG + one parallel
// poll round by wave 0 (no same-address RMW serialization).
//
// LDS: [0,65536) Wh 32rows x 1024k bf16 (2048-B rows, XOR-swz); pre[2][64][33] f32.
#define LDS_BYTES (65536 + 2 * 64 * 33 * 4)

__global__ __launch_bounds__(256) void lstm_persist(
    const short* __restrict__ gx,   // [S][64][4096]
    const short* __restrict__ wh,   // [4096][1024]
    char* __restrict__ hb,          // rotating h slots, HSTRIDE apart
    unsigned int* __restrict__ flags, // [NWG*FLAGSTRIDE]
    float* __restrict__ out) {
  extern __shared__ __align__(16) char lds[];
  char* WhC = lds;
  float (*pre)[64][33] = (float(*)[64][33])(lds + 65536);

  const int tid = threadIdx.x, wave = tid >> 6, lane = tid & 63;
  const int r0 = blockIdx.x * 32;
  const int j0 = blockIdx.x * 8;
  const char* whB = (const char*)(wh + (size_t)r0 * NH);

  // ---- load Wh once, swizzled via pre-swizzled global source (rule #21) ----
#pragma unroll
  for (int p = 0; p < 16; ++p) {
    int L = p * 4096 + tid * 16;
    int row = L >> 11, kb = L & 2047;
    gload16(whB + (size_t)row * 2048 + (kb ^ ((row & 7) << 4)), lds + L);
  }

  const int b_pw = tid >> 2;            // pointwise: this thread's batch
  const int jj0  = (tid & 3) * 2;       // j-pair base within WG's 8 j
  float c_reg[2] = {0.f, 0.f};

  // A-fragment addressing: batch row + k-chunk per lane
  const int am   = wave * 16 + (lane & 15);       // batch row
  const int akb  = (lane >> 4) * 16;              // lane's 16-B k-chunk
  // B (Wh) fragment addressing
  const int b0r = lane & 15, b1r = 16 + (lane & 15);
  const int bs0 = (b0r & 7) << 4, bs1 = (b1r & 7) << 4;
  const int bcol = (lane >> 4) * 16;

  // barrier poll addresses for wave 0: lane watches flags[lane], flags[lane+64]
  const unsigned int* f0 = flags + lane * FLAGSTRIDE;
  const unsigned int* f1 = flags + (lane + 64) * FLAGSTRIDE;

  __syncthreads();   // Wh resident

  // gx fragment for t=0
  bf16x8 gxv = *(const bf16x8*)(gx + (size_t)b_pw * NR + r0 + (tid & 3) * 8);

  for (int t = 0; t < S_LEN; ++t) {
    f32x4 acc[2][2] = {};

    if (t) {   // t=0: h=0 -> matvec contributes nothing
      const char* hs = hb + (size_t)(t - 1) * HSTRIDE + (size_t)am * 2048 + akb;
      // cached 16-B loads straight into A-fragments (L2-shared across WGs/XCD)
      bf16x8 a[32];
#pragma unroll
      for (int ks = 0; ks < 32; ++ks)
        a[ks] = *(const bf16x8*)(hs + ks * 64);
#pragma unroll
      for (int ks = 0; ks < 32; ++ks) {
        int wb = ks * 64 + bcol;
        bf16x8 b0 = *(const bf16x8*)(WhC + b0r * 2048 + (wb ^ bs0));
        bf16x8 b1 = *(const bf16x8*)(WhC + b1r * 2048 + (wb ^ bs1));
        acc[0][ks & 1] = __builtin_amdgcn_mfma_f32_16x16x32_bf16(a[ks], b0, acc[0][ks & 1], 0, 0, 0);
        acc[1][ks & 1] = __builtin_amdgcn_mfma_f32_16x16x32_bf16(a[ks], b1, acc[1][ks & 1], 0, 0, 0);
      }
    }

    // park pre-activations in LDS (parity buffer; remap MFMA layout)
    const int par = t & 1;
    {
      f32x4 a0 = acc[0][0] + acc[0][1];
      f32x4 a1 = acc[1][0] + acc[1][1];
      const int colL = lane & 15;
      const int mB   = wave * 16 + (lane >> 4) * 4;
#pragma unroll
      for (int q = 0; q < 4; ++q) {
        pre[par][mB + q][colL]      = a0[q];
        pre[par][mB + q][colL + 16] = a1[q];
      }
    }
    __syncthreads();

    // pointwise: thread owns (b_pw, jj0..jj0+1)
    float hn2[2];
#pragma unroll
    for (int it = 0; it < 2; ++it) {
      int jj = jj0 + it;
      float vi = pre[par][b_pw][jj * 4 + 0] + bf2f(gxv[it * 4 + 0]);
      float vf = pre[par][b_pw][jj * 4 + 1] + bf2f(gxv[it * 4 + 1]);
      float vg = pre[par][b_pw][jj * 4 + 2] + bf2f(gxv[it * 4 + 2]);
      float vo = pre[par][b_pw][jj * 4 + 3] + bf2f(gxv[it * 4 + 3]);
      float ig = sigm(vi), fg = sigm(vf), gg = tanh_fast(vg), og = sigm(vo);
      c_reg[it] = fg * c_reg[it] + ig * gg;
      hn2[it]   = og * tanh_fast(c_reg[it]);
    }

    // h store: write-through to fabric (2 bf16 in 1 dword) into slot t
    {
      short* hout = (short*)(hb + (size_t)t * HSTRIDE);
      uint32_t hbits = (uint32_t)(uint16_t)f2bf(hn2[0]) |
                       ((uint32_t)(uint16_t)f2bf(hn2[1]) << 16);
      astore32(hout + b_pw * NH + j0 + jj0, hbits);
      float2 of = { hn2[0], hn2[1] };
      *(float2*)(out + ((size_t)t * NB + b_pw) * NH + j0 + jj0) = of;
      if (t == S_LEN - 1) {
        float* oh = out + (size_t)S_LEN * NB * NH;
        int ci = b_pw * NH + j0 + jj0;
        *(float2*)(oh + ci) = of;                                  // final h
        float2 cf = { c_reg[0], c_reg[1] };
        *(float2*)(oh + NB * NH + ci) = cf;                        // final c
      }
    }

    if (t != S_LEN - 1) {
      // prefetch next gx fragment (independent of barrier)
      gxv = *(const bf16x8*)(gx + ((size_t)(t + 1) * NB + b_pw) * NR + r0 + (tid & 3) * 8);

      __syncthreads();   // all waves' h stores acked at coherence point (vmcnt drain)
      const unsigned want = (unsigned)(t + 1);
      if (tid == 0) astore32((void*)(flags + blockIdx.x * FLAGSTRIDE), want);
      if (wave == 0) {
        for (;;) {
          uint32_t v0 = aload32(f0);
          uint32_t v1 = aload32(f1);
          if (__all(v0 >= want && v1 >= want)) break;
          __builtin_amdgcn_s_sleep(1);
        }
      }
      __syncthreads();   // release: h slot t globally visible & fresh
    }
  }
}

// ---------------- launch ----------------

extern "C" void kernel_launch(void* const* d_in, const int* in_sizes, int n_in,
                              void* d_out, int out_size, void* d_ws, size_t ws_size,
                              hipStream_t stream) {
  const float* x   = (const float*)d_in[0];
  const float* wxi = (const float*)d_in[1];
  const float* bxi = (const float*)d_in[2];
  const float* whi = (const float*)d_in[3];
  const float* bhi = (const float*)d_in[4];
  const float* bi  = (const float*)d_in[5];
  const float* wxf = (const float*)d_in[6];
  const float* bxf = (const float*)d_in[7];
  const float* whf = (const float*)d_in[8];
  const float* bhf = (const float*)d_in[9];
  const float* bf  = (const float*)d_in[10];
  const float* wxc = (const float*)d_in[11];
  const float* bxc = (const float*)d_in[12];
  const float* whc = (const float*)d_in[13];
  const float* bhc = (const float*)d_in[14];
  const float* bc  = (const float*)d_in[15];
  const float* wxo = (const float*)d_in[16];
  const float* bxo = (const float*)d_in[17];
  const float* who = (const float*)d_in[18];
  const float* bho = (const float*)d_in[19];
  const float* bo  = (const float*)d_in[20];

  char* ws = (char*)d_ws;
  const size_t SB = (size_t)S_LEN * NB;
  size_t off = 0;
  short* gxp   = (short*)(ws + off); off += SB * NR * 2;        // 268 MB
  short* xbf   = (short*)(ws + off); off += SB * NI * 2;        // 67 MB (dead after gemm_x)
  short* wxcat = (short*)(ws + off); off += (size_t)NR * NI * 2; // 8 MB (dead after gemm_x)
  short* whcat = (short*)(ws + off); off += (size_t)NR * NH * 2;
  float* bias  = (float*)(ws + off); off += NR * 4;
  unsigned int* flags = (unsigned int*)(ws + off); off += NWG * FLAGSTRIDE * 4;
  (void)ws_size; (void)in_sizes; (void)n_in; (void)out_size;

  // rotating h buffer ALIASES xbf+wxcat (both dead once lstm_persist runs):
  // 512 slots x 132096 B = 67.6 MB <= 75.5 MB available.
  char* hb = (char*)xbf;

  float* out = (float*)d_out;

  (void)hipFuncSetAttribute((const void*)lstm_persist,
                            hipFuncAttributeMaxDynamicSharedMemorySize, LDS_BYTES);

  k_convert_x<<<(int)(SB * NI / 4 / 256), 256, 0, stream>>>(x, xbf);
  WPtrs wp = {wxi, wxf, wxc, wxo, whi, whf, whc, who};
  k_pack_w<<<(NR * NI / 4) / 256, 256, 0, stream>>>(wp, wxcat, whcat);
  BPtrs bp = {bxi, bhi, bi, bxf, bhf, bf, bxc, bhc, bc, bxo, bho, bo};
  k_init<<<NR / 256, 256, 0, stream>>>(bp, bias, flags);

  gemm_x<<<dim3(SB / 128, NR / 128), 256, 0, stream>>>(xbf, wxcat, bias, gxp);

  lstm_persist<<<NWG, 256, LDS_BYTES, stream>>>(gxp, whcat, hb, flags, out);
}